// Round 5
// baseline (18.748 us; speedup 1.0000x reference)
//
#include <hip/hip_runtime.h>

#define BATCH 512
#define NNEG  2048
#define DIM   128
#define PADR  132   // q LDS row stride (floats): bank base 4(r+dg) on reads -> conflict-free

// Block: 256 threads (4 waves). Tile: 32 q-rows x 64 tails. Wave w: q-rows [8w,8w+8).
// Lane (dg,tg), dg=lane>>3, tg=lane&7:
//   owns tails {8k+tg, k=0..7} x dims {32j+4dg..32j+4dg+4, j=0..3}  (16 dims/lane)
//   ALL 32 tail float4 loads issued up-front, global -> VGPR (tile is L2-hot,
//   per instr 8 rows x 128B contiguous -> fully coalesced); latency hides under
//   q staging + barrier.
// q = head + relemb[relid] staged once in padded LDS; per row 4x ds_read_b128
//   at words 4(dg+8j): 8 distinct banks, 8-lane broadcast -> conflict-free.
// Partial sums (8 rows x 8 tails x 16 dims per lane) reduced across dg with a
// routed xor tree: ds_swizzle imm (masks 8,16) + shfl_xor(32); lane ends row=dg.

__device__ __forceinline__ float swz8(float v) {
  return __int_as_float(__builtin_amdgcn_ds_swizzle(__float_as_int(v), 0x201F)); // xor 8
}
__device__ __forceinline__ float swz16(float v) {
  return __int_as_float(__builtin_amdgcn_ds_swizzle(__float_as_int(v), 0x401F)); // xor 16
}

__global__ __launch_bounds__(256, 2)
void transe_l1(const float* __restrict__ head,
               const int*   __restrict__ relid,
               const float* __restrict__ tailp,
               const float* __restrict__ relemb,
               float* __restrict__ out) {
  __shared__ float lq[32 * PADR];            // 16,896 B

  const int tid  = threadIdx.x;
  const int bx   = blockIdx.x;
  const int t0   = (bx & 31) * 64;           // 32 tail tiles
  const int b0   = (bx >> 5) * 32;           // 16 batch groups
  const int lane = tid & 63;
  const int w    = tid >> 6;
  const int tg   = lane & 7;
  const int dg   = lane >> 3;

  // ---- (a) q global loads into temps (oldest in flight) ----
  float4 h[4], e[4];
  int rr[4], gg[4];
#pragma unroll
  for (int m = 0; m < 4; ++m) {
    int k = tid + m * 256;                   // 0..1023
    rr[m] = k >> 5; gg[m] = k & 31;
    int b = b0 + rr[m];
    int rid = relid[b];
    h[m] = *reinterpret_cast<const float4*>(&head[b * DIM + gg[m] * 4]);
    e[m] = *reinterpret_cast<const float4*>(&relemb[rid * DIM + gg[m] * 4]);
  }

  // ---- (b) tail fragments: 32x global_load_dwordx4, all independent ----
  const float* tbase = tailp + (size_t)(t0 + tg) * DIM + 4 * dg;
  float4 tf[8][4];
#pragma unroll
  for (int k = 0; k < 8; ++k) {
#pragma unroll
    for (int j = 0; j < 4; ++j)
      tf[k][j] = *reinterpret_cast<const float4*>(tbase + (size_t)(8 * k) * DIM + 32 * j);
  }

  // ---- (c) q = head + rel -> LDS (padded layout; 2-way write = free) ----
#pragma unroll
  for (int m = 0; m < 4; ++m) {
    float4 v;
    v.x = h[m].x + e[m].x; v.y = h[m].y + e[m].y;
    v.z = h[m].z + e[m].z; v.w = h[m].w + e[m].w;
    *reinterpret_cast<float4*>(&lq[rr[m] * PADR + gg[m] * 4]) = v;
  }
  __syncthreads();

  float acc[8][8];
#pragma unroll
  for (int r = 0; r < 8; ++r)
#pragma unroll
    for (int k = 0; k < 8; ++k) acc[r][k] = 0.f;

  const float* lqw = lq + (w * 8) * PADR;    // wave's 8 q-rows

#pragma unroll
  for (int r = 0; r < 8; ++r) {
    float4 q0 = *reinterpret_cast<const float4*>(&lqw[r * PADR + (dg +  0) * 4]);
    float4 q1 = *reinterpret_cast<const float4*>(&lqw[r * PADR + (dg +  8) * 4]);
    float4 q2 = *reinterpret_cast<const float4*>(&lqw[r * PADR + (dg + 16) * 4]);
    float4 q3 = *reinterpret_cast<const float4*>(&lqw[r * PADR + (dg + 24) * 4]);
#pragma unroll
    for (int k = 0; k < 8; ++k) {
      float s = acc[r][k];
      s += fabsf(q0.x - tf[k][0].x);
      s += fabsf(q0.y - tf[k][0].y);
      s += fabsf(q0.z - tf[k][0].z);
      s += fabsf(q0.w - tf[k][0].w);
      s += fabsf(q1.x - tf[k][1].x);
      s += fabsf(q1.y - tf[k][1].y);
      s += fabsf(q1.z - tf[k][1].z);
      s += fabsf(q1.w - tf[k][1].w);
      s += fabsf(q2.x - tf[k][2].x);
      s += fabsf(q2.y - tf[k][2].y);
      s += fabsf(q2.z - tf[k][2].z);
      s += fabsf(q2.w - tf[k][2].w);
      s += fabsf(q3.x - tf[k][3].x);
      s += fabsf(q3.y - tf[k][3].y);
      s += fabsf(q3.z - tf[k][3].z);
      s += fabsf(q3.w - tf[k][3].w);
      acc[r][k] = s;
    }
  }

  // ---- routed reduction across dg (masks 8/16 via ds_swizzle, 32 via shfl) ----
  const int brow = b0 + w * 8 + dg;
#pragma unroll
  for (int k = 0; k < 8; ++k) {
    float s4[4];
#pragma unroll
    for (int i = 0; i < 4; ++i) {
      float a  = acc[2 * i][k], b = acc[2 * i + 1][k];
      float xa = swz8(a), xb = swz8(b);
      s4[i] = (dg & 1) ? (b + xb) : (a + xa);       // keep rows with r0 == dg0
    }
    float s2[2];
#pragma unroll
    for (int i = 0; i < 2; ++i) {
      float a  = s4[2 * i], b = s4[2 * i + 1];
      float xa = swz16(a), xb = swz16(b);
      s2[i] = (dg & 2) ? (b + xb) : (a + xa);       // keep rows with r1 == dg1
    }
    float a  = s2[0], b = s2[1];
    float xa = __shfl_xor(a, 32), xb = __shfl_xor(b, 32);
    float v  = (dg & 4) ? (b + xb) : (a + xa);      // row r2 == dg2 -> row = dg
    out[(size_t)brow * NNEG + t0 + 8 * k + tg] = -v;
  }
}

extern "C" void kernel_launch(void* const* d_in, const int* in_sizes, int n_in,
                              void* d_out, int out_size, void* d_ws, size_t ws_size,
                              hipStream_t stream) {
  const float* head   = (const float*)d_in[0];
  const int*   relid  = (const int*)d_in[1];
  const float* tailp  = (const float*)d_in[2];
  const float* relemb = (const float*)d_in[3];
  float*       out    = (float*)d_out;

  transe_l1<<<dim3(512), dim3(256), 0, stream>>>(head, relid, tailp, relemb, out);
}

// Round 8
// 13.678 us; speedup vs baseline: 1.3706x; 1.3706x over previous
//
#include <hip/hip_runtime.h>

#define BATCH 512
#define NNEG  2048
#define DIM   128

// Block: 256 threads (4 waves). Tile: 32 q-rows x 64 tails. Wave w: q-rows [8w,8w+8).
// Lane (dg,tg), dg=lane>>3, tg=lane&7: owns tails {8k+tg, k=0..7} x dims [16dg,16dg+16).
// BOTH operands use the same dim convention (R3-proven):
//   tails: granule (r,g) at word r*128 + 4*(g ^ (r&7)); tf[k][j] read at p=(4dg+j)^tg.
//   q:     granule (r,g) at word r*128 + 4*((g>>2) + (g&3)*8); read at word (dg+8j)*4
//          -> original granule 4dg+j -> dims [16dg+4j, 16dg+4j+4).  (permuted write!)
// Reduction across dg: masks 32/16 on the VALU pipe via v_permlane{32,16}_swap_b32
// (derived: dst'/src' = row-swap; swap+add routes row i to lane half, final row = dg),
// mask 8 via ds_swizzle. Runtime direction probe + proven all-DS fallback kept as insurance.

__device__ __forceinline__ float swz8(float v) {
  return __int_as_float(__builtin_amdgcn_ds_swizzle(__float_as_int(v), 0x201F)); // xor 8
}
__device__ __forceinline__ float swz16(float v) {
  return __int_as_float(__builtin_amdgcn_ds_swizzle(__float_as_int(v), 0x401F)); // xor 16
}

__device__ __forceinline__ void plswap32(float& a, float& b) {
#if __has_builtin(__builtin_amdgcn_permlane32_swap)
  auto r = __builtin_amdgcn_permlane32_swap(__float_as_uint(a), __float_as_uint(b), false, false);
  a = __uint_as_float(r[0]); b = __uint_as_float(r[1]);
#else
  asm("v_permlane32_swap_b32 %0, %1" : "+v"(a), "+v"(b));
#endif
}
__device__ __forceinline__ void plswap16(float& a, float& b) {
#if __has_builtin(__builtin_amdgcn_permlane16_swap)
  auto r = __builtin_amdgcn_permlane16_swap(__float_as_uint(a), __float_as_uint(b), false, false);
  a = __uint_as_float(r[0]); b = __uint_as_float(r[1]);
#else
  asm("v_permlane16_swap_b32 %0, %1" : "+v"(a), "+v"(b));
#endif
}

__global__ __launch_bounds__(256, 2)
void transe_l1(const float* __restrict__ head,
               const int*   __restrict__ relid,
               const float* __restrict__ tailp,
               const float* __restrict__ relemb,
               float* __restrict__ out) {
  __shared__ float lt[64 * 128];             // 32,768 B (tails, XOR-swizzled granules)
  __shared__ float lq[32 * 128];             // 16,384 B (q, permuted granules)

  const int tid  = threadIdx.x;
  const int bx   = blockIdx.x;
  const int t0   = (bx & 31) * 64;
  const int b0   = (bx >> 5) * 32;
  const int lane = tid & 63;
  const int w    = tid >> 6;
  const int tg   = lane & 7;
  const int dg   = lane >> 3;

  // ---- stage tails: coalesced global read, XOR-swizzled LDS write (R3-proven) ----
#pragma unroll
  for (int m = 0; m < 8; ++m) {
    int k = tid + m * 256;
    int r = k >> 5, g = k & 31;
    float4 v = *reinterpret_cast<const float4*>(&tailp[(size_t)(t0 + r) * DIM + g * 4]);
    int p = g ^ (r & 7);
    *reinterpret_cast<float4*>(&lt[r * 128 + p * 4]) = v;
  }
  // ---- stage q = head + relemb[relid[b]]: PERMUTED write (R3-proven) ----
#pragma unroll
  for (int m = 0; m < 4; ++m) {
    int k = tid + m * 256;
    int r = k >> 5, g = k & 31;
    int b = b0 + r;
    int rid = relid[b];
    float4 h = *reinterpret_cast<const float4*>(&head[b * DIM + g * 4]);
    float4 e = *reinterpret_cast<const float4*>(&relemb[rid * DIM + g * 4]);
    float4 v;
    v.x = h.x + e.x; v.y = h.y + e.y; v.z = h.z + e.z; v.w = h.w + e.w;
    int p = (g >> 2) + (g & 3) * 8;          // dg-major permutation
    *reinterpret_cast<float4*>(&lq[r * 128 + p * 4]) = v;
  }
  __syncthreads();

  // ---- tail fragment -> 128 VGPRs: tf[k][j] = tails[8k+tg][16dg+4j..] (R3-proven) ----
  float4 tf[8][4];
#pragma unroll
  for (int k = 0; k < 8; ++k) {
#pragma unroll
    for (int j = 0; j < 4; ++j) {
      int p = (4 * dg + j) ^ tg;
      tf[k][j] = *reinterpret_cast<const float4*>(&lt[(8 * k + tg) * 128 + p * 4]);
    }
  }

  float acc[8][8];
#pragma unroll
  for (int r = 0; r < 8; ++r)
#pragma unroll
    for (int k = 0; k < 8; ++k) acc[r][k] = 0.f;

  const int qbase = (w * 8) * 128;

#pragma unroll
  for (int r = 0; r < 8; ++r) {
    float4 qf[4];
#pragma unroll
    for (int j = 0; j < 4; ++j)              // word (dg+8j)*4 == original granule 4dg+j
      qf[j] = *reinterpret_cast<const float4*>(&lq[qbase + r * 128 + (dg + 8 * j) * 4]);
#pragma unroll
    for (int k = 0; k < 8; ++k) {
      float s = acc[r][k];
#pragma unroll
      for (int j = 0; j < 4; ++j) {
        s += fabsf(qf[j].x - tf[k][j].x);
        s += fabsf(qf[j].y - tf[k][j].y);
        s += fabsf(qf[j].z - tf[k][j].z);
        s += fabsf(qf[j].w - tf[k][j].w);
      }
      acc[r][k] = s;
    }
  }

  // ---- probe permlane swap direction (wave-uniform, once; insurance) ----
  int mode32, mode16;
  {
    float pa = (float)lane, pb = (float)lane + 100.0f;
    float a32 = pa, b32 = pb;
    plswap32(a32, b32);
    float s32 = a32 + b32;
    float a16 = pa, b16 = pb;
    plswap16(a16, b16);
    float s16 = a16 + b16;
    float f0  = __int_as_float(__builtin_amdgcn_readfirstlane(__float_as_int(s32)));
    float f32 = __int_as_float(__builtin_amdgcn_readlane(__float_as_int(s32), 32));
    float g0  = __int_as_float(__builtin_amdgcn_readfirstlane(__float_as_int(s16)));
    float g16 = __int_as_float(__builtin_amdgcn_readlane(__float_as_int(s16), 16));
    mode32 = (f0 == 32.0f && f32 == 232.0f) ? 0 : (f0 == 232.0f && f32 == 32.0f) ? 1 : -1;
    mode16 = (g0 == 16.0f && g16 == 216.0f) ? 0 : (g0 == 216.0f && g16 == 16.0f) ? 1 : -1;
  }

  if (mode32 >= 0 && mode16 >= 0) {
    // permlane path: row = dg0 + 2*(dg1^mode16) + 4*(dg2^mode32)  (== dg when modes are 0)
    const int row  = (dg & 1) + 2 * (((dg >> 1) & 1) ^ mode16) + 4 * (((dg >> 2) & 1) ^ mode32);
    const int brow = b0 + w * 8 + row;
#pragma unroll
    for (int k = 0; k < 8; ++k) {
      float s4[4];
#pragma unroll
      for (int i = 0; i < 4; ++i) {          // mask-32 level: rows i / i+4
        float a = acc[i][k], b = acc[i + 4][k];
        plswap32(a, b);
        s4[i] = a + b;
      }
      float s2[2];
#pragma unroll
      for (int i = 0; i < 2; ++i) {          // mask-16 level: rows i / i+2
        float a = s4[i], b = s4[i + 2];
        plswap16(a, b);
        s2[i] = a + b;
      }
      float a  = s2[0], b = s2[1];           // mask-8 level (DS swizzle, proven)
      float xa = swz8(a), xb = swz8(b);
      float v  = (dg & 1) ? (b + xb) : (a + xa);
      out[(size_t)brow * NNEG + t0 + 8 * k + tg] = -v;
    }
  } else {
    // fallback: proven all-DS routed tree, row = dg
    const int brow = b0 + w * 8 + dg;
#pragma unroll
    for (int k = 0; k < 8; ++k) {
      float s4[4];
#pragma unroll
      for (int i = 0; i < 4; ++i) {
        float a  = acc[2 * i][k], b = acc[2 * i + 1][k];
        float xa = swz8(a), xb = swz8(b);
        s4[i] = (dg & 1) ? (b + xb) : (a + xa);
      }
      float s2[2];
#pragma unroll
      for (int i = 0; i < 2; ++i) {
        float a  = s4[2 * i], b = s4[2 * i + 1];
        float xa = swz16(a), xb = swz16(b);
        s2[i] = (dg & 2) ? (b + xb) : (a + xa);
      }
      float a  = s2[0], b = s2[1];
      float xa = __shfl_xor(a, 32), xb = __shfl_xor(b, 32);
      float v  = (dg & 4) ? (b + xb) : (a + xa);
      out[(size_t)brow * NNEG + t0 + 8 * k + tg] = -v;
    }
  }
}

extern "C" void kernel_launch(void* const* d_in, const int* in_sizes, int n_in,
                              void* d_out, int out_size, void* d_ws, size_t ws_size,
                              hipStream_t stream) {
  const float* head   = (const float*)d_in[0];
  const int*   relid  = (const int*)d_in[1];
  const float* tailp  = (const float*)d_in[2];
  const float* relemb = (const float*)d_in[3];
  float*       out    = (float*)d_out;

  transe_l1<<<dim3(512), dim3(256), 0, stream>>>(head, relid, tailp, relemb, out);
}